// Round 7
// baseline (243.883 us; speedup 1.0000x reference)
//
#include <hip/hip_runtime.h>
#include <hip/hip_bf16.h>

typedef __bf16 bf8 __attribute__((ext_vector_type(8)));
typedef float f32x4 __attribute__((ext_vector_type(4)));

#define NF 160
#define NC 10
// w = exp(-d/1.1) = exp2(-sqrt(C2 * d^2)), C2 = (log2e/1.1)^2
#define WSCALE (-1.4426950408889634f / 1.1f)
#define C2SCALE (WSCALE * WSCALE)
#define NEG2C2 (-2.0f * C2SCALE)

// Unified packed tile: 32 addr rows, 12288 B:
//   [    0,10240): K frags  [half(2)][kk(5)][lane(64)][8 bf16]
//   [10240,11264): M frags  [lane(64)][8 bf16]   (PV A-operand, ones col 10)
//   [11264,11392): y2*C2    f32[32]
//   [11392,12288): zero pad (makes staging 768 x 16B = 3 even loads/thread)
#define TILE_E 6144   // bf16 elements
#define TILE_B 12288  // bytes

// ---------------------------------------------------------------------------
__device__ __forceinline__ void gload_lds16(const __bf16* gsrc, __bf16* ldst) {
    __builtin_amdgcn_global_load_lds(
        (const __attribute__((address_space(1))) unsigned int*)gsrc,
        (__attribute__((address_space(3))) unsigned int*)ldst,
        16, 0, 0);
}

__device__ __forceinline__ void stage_tile(const __bf16* src, __bf16* dst, int t) {
    gload_lds16(src + (size_t)t * 8,           dst + (size_t)t * 8);
    gload_lds16(src + ((size_t)256 + t) * 8,   dst + ((size_t)256 + t) * 8);
    gload_lds16(src + ((size_t)512 + t) * 8,   dst + ((size_t)512 + t) * 8);
}

// ===========================================================================
// PRE-PASS: build unified tiles.
// ===========================================================================
__global__ __launch_bounds__(256)
void pack_kernel(const float* __restrict__ addr, const float* __restrict__ Mm,
                 __bf16* __restrict__ pk, int A)
{
    const int nkb = A / 64;
    const int lane = threadIdx.x & 63;
    const int w    = threadIdx.x >> 6;
    const int l15  = lane & 15;
    const int g    = lane >> 4;

    if ((int)blockIdx.x < nkb) {
        const int b = blockIdx.x * 4 + w;       // 16-row block
        const int p = b >> 1, h = b & 1;        // tile, half
        const float* row = addr + (size_t)(b * 16 + l15) * NF;
        __bf16* dst = pk + (size_t)p * TILE_E + h * 2560;
        float ss = 0.f;
        #pragma unroll
        for (int kk = 0; kk < 5; ++kk) {
            float4 lo = *(const float4*)(row + 32 * kk + 4 * g);
            float4 hi = *(const float4*)(row + 32 * kk + 4 * g + 16);
            ss += lo.x*lo.x + lo.y*lo.y + lo.z*lo.z + lo.w*lo.w
                + hi.x*hi.x + hi.y*hi.y + hi.z*hi.z + hi.w*hi.w;
            bf8 f;
            f[0]=(__bf16)lo.x; f[1]=(__bf16)lo.y; f[2]=(__bf16)lo.z; f[3]=(__bf16)lo.w;
            f[4]=(__bf16)hi.x; f[5]=(__bf16)hi.y; f[6]=(__bf16)hi.z; f[7]=(__bf16)hi.w;
            *(bf8*)(dst + kk * 512 + lane * 8) = f;
        }
        ss += __shfl_xor(ss, 16, 64);
        ss += __shfl_xor(ss, 32, 64);
        if (g == 0)
            ((float*)(pk + (size_t)p * TILE_E + 5632))[h * 16 + l15] = ss * C2SCALE;
    } else {
        const int mb = (blockIdx.x - nkb) * 4 + w;   // tile index (32 rows)
        bf8 f;
        #pragma unroll
        for (int e = 0; e < 8; ++e) {
            int r = mb * 32 + 4 * g + (e & 3) + 16 * (e >> 2);
            float v = (l15 < NC) ? Mm[(size_t)r * NC + l15] : (l15 == NC ? 1.0f : 0.0f);
            f[e] = (__bf16)v;
        }
        *(bf8*)(pk + (size_t)mb * TILE_E + 5120 + lane * 8) = f;
        if (lane < 56) {                              // zero pad 896 B
            uint4 z = {0u, 0u, 0u, 0u};
            *(uint4*)(pk + (size_t)mb * TILE_E + 5696 + lane * 8) = z;
        }
    }
}

// ===========================================================================
// MAIN: minimal 2-phase pipeline (T3): stage(t+1) -> compute(t) -> vmcnt(0)
// -> raw s_barrier. NO register global-loads in the loop (all via LDS).
// LDS 24576 B -> 6 blocks/CU; grid (N/128)*48 = 1536 = exactly 6/CU.
// ===========================================================================
__global__ __launch_bounds__(256, 6)
void fused_fast(const float* __restrict__ inp,
                const __bf16* __restrict__ pk,
                float* __restrict__ part,
                int N, int S, int ntt)
{
    __shared__ __align__(16) __bf16 kbuf[2][TILE_E];

    const int bid   = blockIdx.x;
    const int split = bid % S;
    const int qblk  = bid / S;
    const int t     = threadIdx.x;
    const int lane  = t & 63;
    const int wave  = t >> 6;
    const int l15   = lane & 15;
    const int g     = lane >> 4;

    // ---- hoist Q fragments + x2*C2 (per wave's own 32 queries)
    const int qbase = qblk * 128 + wave * 32;
    bf8 qfrag[2][5];
    float x2q[2];
    #pragma unroll
    for (int qf = 0; qf < 2; ++qf) {
        const float* qrow = inp + (size_t)(qbase + qf * 16 + l15) * NF;
        float ss = 0.f;
        #pragma unroll
        for (int kk = 0; kk < 5; ++kk) {
            float4 lo = *(const float4*)(qrow + 32 * kk + 4 * g);
            float4 hi = *(const float4*)(qrow + 32 * kk + 4 * g + 16);
            ss += lo.x*lo.x + lo.y*lo.y + lo.z*lo.z + lo.w*lo.w
                + hi.x*hi.x + hi.y*hi.y + hi.z*hi.z + hi.w*hi.w;
            bf8 f;
            f[0]=(__bf16)lo.x; f[1]=(__bf16)lo.y; f[2]=(__bf16)lo.z; f[3]=(__bf16)lo.w;
            f[4]=(__bf16)hi.x; f[5]=(__bf16)hi.y; f[6]=(__bf16)hi.z; f[7]=(__bf16)hi.w;
            qfrag[qf][kk] = f;
        }
        ss += __shfl_xor(ss, 16, 64);
        ss += __shfl_xor(ss, 32, 64);
        x2q[qf] = ss * C2SCALE;
    }

    f32x4 acc[2];
    #pragma unroll
    for (int qf = 0; qf < 2; ++qf) acc[qf] = (f32x4){0.f, 0.f, 0.f, 0.f};

    // variable split range (S need not divide ntt)
    const int ts = (split * ntt) / S;
    const int nt = ((split + 1) * ntt) / S - ts;
    const __bf16* src = pk + (size_t)ts * TILE_E;

    // ---- prologue
    stage_tile(src, &kbuf[0][0], t);
    asm volatile("s_waitcnt vmcnt(0)" ::: "memory");
    __builtin_amdgcn_s_barrier();

    int cur = 0;
    for (int it = 0; it < nt; ++it) {
        if (it + 1 < nt)
            stage_tile(src + (size_t)(it + 1) * TILE_E, &kbuf[cur ^ 1][0], t);

        const __bf16* kb = &kbuf[cur][0];
        // M fragment + y2 from LDS (lgkmcnt path, no FIFO drain)
        bf8 mf = *(const bf8*)(kb + 5120 + lane * 8);
        float y2r[8];
        {
            const float* y2p = (const float*)(kb + 5632);
            #pragma unroll
            for (int m = 0; m < 2; ++m) {
                f32x4 yv = *(const f32x4*)(y2p + m * 16 + 4 * g);
                y2r[m*4+0] = yv[0]; y2r[m*4+1] = yv[1];
                y2r[m*4+2] = yv[2]; y2r[m*4+3] = yv[3];
            }
        }
        bf8 kf[2][5];
        #pragma unroll
        for (int m = 0; m < 2; ++m)
            #pragma unroll
            for (int kk = 0; kk < 5; ++kk)
                kf[m][kk] = *(const bf8*)(kb + m * 2560 + kk * 512 + lane * 8);

        #pragma unroll
        for (int qf = 0; qf < 2; ++qf) {
            f32x4 s0 = {0.f,0.f,0.f,0.f}, s1 = {0.f,0.f,0.f,0.f};
            #pragma unroll
            for (int kk = 0; kk < 5; ++kk) {
                s0 = __builtin_amdgcn_mfma_f32_16x16x32_bf16(kf[0][kk], qfrag[qf][kk], s0, 0, 0, 0);
                s1 = __builtin_amdgcn_mfma_f32_16x16x32_bf16(kf[1][kk], qfrag[qf][kk], s1, 0, 0, 0);
            }
            bf8 p;
            const float xq = x2q[qf];
            #pragma unroll
            for (int r = 0; r < 4; ++r) {
                float d2a = fmaf(s0[r], NEG2C2, xq + y2r[r]);
                float d2b = fmaf(s1[r], NEG2C2, xq + y2r[4 + r]);
                float da = __builtin_amdgcn_sqrtf(d2a);
                float db = __builtin_amdgcn_sqrtf(d2b);
                p[r]     = (__bf16)__builtin_amdgcn_exp2f(-da);
                p[4 + r] = (__bf16)__builtin_amdgcn_exp2f(-db);
            }
            acc[qf] = __builtin_amdgcn_mfma_f32_16x16x32_bf16(mf, p, acc[qf], 0, 0, 0);
        }

        // tile t+1's loads had the whole compute to land; drain is ~free
        asm volatile("s_waitcnt vmcnt(0)" ::: "memory");
        __builtin_amdgcn_s_barrier();
        cur ^= 1;
    }

    // ---- epilogue: partials [S][N][12] (cols 0..9 = num, col 10 = denom)
    #pragma unroll
    for (int qf = 0; qf < 2; ++qf) {
        if (g < 3) {
            const int q = qbase + qf * 16 + l15;
            *(f32x4*)(part + ((size_t)split * N + q) * 12 + 4 * g) = acc[qf];
        }
    }
}

// 4 threads per query, shfl-reduce, lane0-of-4 writes.
__global__ void combine_kernel(const float* __restrict__ ws, float* __restrict__ out,
                               int N, int nsplit)
{
    int gid = blockIdx.x * blockDim.x + threadIdx.x;
    int q = gid >> 2, part = gid & 3;
    if (q >= N) return;
    f32x4 n0 = {0.f,0.f,0.f,0.f}, n1 = {0.f,0.f,0.f,0.f}, n2 = {0.f,0.f,0.f,0.f};
    for (int s = part; s < nsplit; s += 4) {
        const float* p = ws + ((size_t)s * N + q) * 12;
        n0 += *(const f32x4*)(p);
        n1 += *(const f32x4*)(p + 4);
        n2 += *(const f32x4*)(p + 8);
    }
    #pragma unroll
    for (int d = 1; d < 4; d <<= 1) {
        #pragma unroll
        for (int i = 0; i < 4; ++i) {
            n0[i] += __shfl_xor(n0[i], d, 64);
            n1[i] += __shfl_xor(n1[i], d, 64);
            n2[i] += __shfl_xor(n2[i], d, 64);
        }
    }
    if (part == 0) {
        float inv = 1.f / n2[2];
        float o[NC] = {n0[0],n0[1],n0[2],n0[3],n1[0],n1[1],n1[2],n1[3],n2[0],n2[1]};
        #pragma unroll
        for (int c = 0; c < NC; ++c) out[(size_t)q * NC + c] = o[c] * inv;
    }
}

// ===========================================================================
// FALLBACK (round-1 kernel): used only if ws too small for the packed path.
// ===========================================================================
#define QB 64
#define KVB 128
#define KPAD 164
#define MPAD 18

__global__ __launch_bounds__(256, 2)
void fused_dist_softmin(const float* __restrict__ inp,
                        const float* __restrict__ addr,
                        const float* __restrict__ Mm,
                        float* __restrict__ ws,
                        float* __restrict__ outp,
                        int N, int nsplit, int a_per_split, int direct)
{
    __shared__ __align__(16) __bf16 Klds[KVB][KPAD];
    __shared__ __align__(16) __bf16 Mlds[KVB][MPAD];
    __shared__ float y2lds[KVB];
    __shared__ float x2lds[QB];
    __shared__ float redbuf[4][4][16][16];

    const int bid = blockIdx.x;
    int split, qblock;
    if (nsplit == 8) { split = bid & 7; qblock = bid >> 3; }
    else             { split = bid % nsplit; qblock = bid / nsplit; }

    const int t    = threadIdx.x;
    const int lane = t & 63;
    const int wave = t >> 6;
    const int l15  = lane & 15;
    const int g    = lane >> 4;
    const int foff = 4 * g;

    if (t < QB) {
        const float* row = inp + (size_t)(qblock * QB + t) * NF;
        float s = 0.f;
        #pragma unroll
        for (int i = 0; i < NF/4; ++i) {
            float4 v = *(const float4*)(row + 4*i);
            s += v.x*v.x + v.y*v.y + v.z*v.z + v.w*v.w;
        }
        x2lds[t] = s;
    }

    bf8 qfrag[4][5];
    #pragma unroll
    for (int qf = 0; qf < 4; ++qf) {
        const float* qrow = inp + (size_t)(qblock*QB + qf*16 + l15) * NF;
        #pragma unroll
        for (int kk = 0; kk < 5; ++kk) {
            float4 lo = *(const float4*)(qrow + 32*kk + foff);
            float4 hi = *(const float4*)(qrow + 32*kk + foff + 16);
            bf8 f;
            f[0]=(__bf16)lo.x; f[1]=(__bf16)lo.y; f[2]=(__bf16)lo.z; f[3]=(__bf16)lo.w;
            f[4]=(__bf16)hi.x; f[5]=(__bf16)hi.y; f[6]=(__bf16)hi.z; f[7]=(__bf16)hi.w;
            qfrag[qf][kk] = f;
        }
    }

    __syncthreads();
    float x2q[4];
    #pragma unroll
    for (int qf = 0; qf < 4; ++qf) x2q[qf] = x2lds[qf*16 + l15];

    f32x4 acc[4];
    #pragma unroll
    for (int qf = 0; qf < 4; ++qf) acc[qf] = (f32x4){0.f,0.f,0.f,0.f};

    const int wa      = wave * 32;
    const int a_begin = split * a_per_split;
    const int ntiles  = a_per_split / KVB;

    for (int tile = 0; tile < ntiles; ++tile) {
        const int a0 = a_begin + tile * KVB;
        __syncthreads();
        {
            const int r = t >> 1, h = t & 1;
            const float* rowp = addr + (size_t)(a0 + r) * NF + h*80;
            float ss = 0.f;
            #pragma unroll
            for (int i = 0; i < 20; ++i) {
                float4 v = *(const float4*)(rowp + 4*i);
                ss += v.x*v.x + v.y*v.y + v.z*v.z + v.w*v.w;
                union { __bf16 b[4]; uint2 u; } pk2;
                pk2.b[0]=(__bf16)v.x; pk2.b[1]=(__bf16)v.y;
                pk2.b[2]=(__bf16)v.z; pk2.b[3]=(__bf16)v.w;
                *(uint2*)&Klds[r][h*80 + 4*i] = pk2.u;
            }
            ss += __shfl_xor(ss, 1, 64);
            if (h == 0) y2lds[r] = ss;
        }
        for (int j = t; j < KVB*NC; j += 256) {
            int r = j / NC, c = j % NC;
            Mlds[r][c] = (__bf16)Mm[(size_t)(a0 + r)*NC + c];
        }
        for (int j = t; j < KVB*8; j += 256) {
            int r = j >> 3, c = 10 + (j & 7);
            Mlds[r][c] = (c == 10) ? (__bf16)1.0f : (__bf16)0.0f;
        }
        __syncthreads();

        bf8 kfrag[2][5];
        #pragma unroll
        for (int m = 0; m < 2; ++m) {
            const __bf16* krow = &Klds[wa + 16*m + l15][0];
            #pragma unroll
            for (int kk = 0; kk < 5; ++kk) {
                uint2 lo = *(const uint2*)(krow + 32*kk + foff);
                uint2 hi = *(const uint2*)(krow + 32*kk + foff + 16);
                union { unsigned int u[4]; bf8 v; } fr;
                fr.u[0]=lo.x; fr.u[1]=lo.y; fr.u[2]=hi.x; fr.u[3]=hi.y;
                kfrag[m][kk] = fr.v;
            }
        }
        float y2r[8];
        #pragma unroll
        for (int m = 0; m < 2; ++m)
            #pragma unroll
            for (int r = 0; r < 4; ++r)
                y2r[m*4 + r] = y2lds[wa + 16*m + 4*g + r];

        bf8 mfrag;
        #pragma unroll
        for (int e = 0; e < 8; ++e)
            mfrag[e] = Mlds[wa + 4*g + (e & 3) + 16*(e >> 2)][l15];

        #pragma unroll
        for (int qf = 0; qf < 4; ++qf) {
            f32x4 s0 = {0.f,0.f,0.f,0.f}, s1 = {0.f,0.f,0.f,0.f};
            #pragma unroll
            for (int kk = 0; kk < 5; ++kk) {
                s0 = __builtin_amdgcn_mfma_f32_16x16x32_bf16(kfrag[0][kk], qfrag[qf][kk], s0, 0, 0, 0);
                s1 = __builtin_amdgcn_mfma_f32_16x16x32_bf16(kfrag[1][kk], qfrag[qf][kk], s1, 0, 0, 0);
            }
            bf8 p;
            const float xq = x2q[qf];
            #pragma unroll
            for (int r = 0; r < 4; ++r) {
                float d2a = xq + y2r[r]     - 2.f*s0[r];
                float d2b = xq + y2r[4 + r] - 2.f*s1[r];
                float da = __builtin_amdgcn_sqrtf(d2a);
                float db = __builtin_amdgcn_sqrtf(d2b);
                p[r]     = (__bf16)__builtin_amdgcn_exp2f(da * WSCALE);
                p[4 + r] = (__bf16)__builtin_amdgcn_exp2f(db * WSCALE);
            }
            acc[qf] = __builtin_amdgcn_mfma_f32_16x16x32_bf16(mfrag, p, acc[qf], 0, 0, 0);
        }
    }

    #pragma unroll
    for (int qf = 0; qf < 4; ++qf)
        #pragma unroll
        for (int r = 0; r < 4; ++r)
            redbuf[wave][qf][4*g + r][l15] = acc[qf][r];
    __syncthreads();

    const int qf2 = t >> 6;
    const int qq  = (t >> 2) & 15;
    const int cg  = t & 3;
    float v[4];
    #pragma unroll
    for (int i = 0; i < 4; ++i) {
        const int c = cg*4 + i;
        v[i] = redbuf[0][qf2][c][qq] + redbuf[1][qf2][c][qq]
             + redbuf[2][qf2][c][qq] + redbuf[3][qf2][c][qq];
    }
    const int qg = qblock*QB + qf2*16 + qq;
    if (!direct) {
        float4 o; o.x=v[0]; o.y=v[1]; o.z=v[2]; o.w=v[3];
        *(float4*)(ws + ((size_t)split * N + qg) * 16 + cg*4) = o;
    } else {
        float den = redbuf[0][qf2][10][qq] + redbuf[1][qf2][10][qq]
                  + redbuf[2][qf2][10][qq] + redbuf[3][qf2][10][qq];
        float inv = 1.f / den;
        #pragma unroll
        for (int i = 0; i < 4; ++i) {
            int c = cg*4 + i;
            if (c < NC) outp[(size_t)qg * NC + c] = v[i] * inv;
        }
    }
}

__global__ void combine16_kernel(const float* __restrict__ ws, float* __restrict__ out,
                                 int N, int nsplit)
{
    int q = blockIdx.x * blockDim.x + threadIdx.x;
    if (q >= N) return;
    float num[NC];
    #pragma unroll
    for (int c = 0; c < NC; ++c) num[c] = 0.f;
    float den = 0.f;
    for (int s = 0; s < nsplit; ++s) {
        const float* p = ws + ((size_t)s * N + q) * 16;
        #pragma unroll
        for (int c = 0; c < NC; ++c) num[c] += p[c];
        den += p[10];
    }
    float inv = 1.f / den;
    #pragma unroll
    for (int c = 0; c < NC; ++c) out[(size_t)q * NC + c] = num[c] * inv;
}

// ===========================================================================
extern "C" void kernel_launch(void* const* d_in, const int* in_sizes, int n_in,
                              void* d_out, int out_size, void* d_ws, size_t ws_size,
                              hipStream_t stream)
{
    const float* inp  = (const float*)d_in[0];
    const float* addr = (const float*)d_in[1];
    const float* Mm   = (const float*)d_in[2];
    float* out = (float*)d_out;

    const int N = in_sizes[0] / NF;   // 4096
    const int A = in_sizes[1] / NF;   // 32768

    const size_t packed = (size_t)(A / 32) * TILE_B;

    int S = 0;
    const int cand[4] = {48, 32, 16, 8};
    for (int i = 0; i < 4; ++i) {
        int s = cand[i];
        if (packed + (size_t)s * N * 48 <= ws_size) { S = s; break; }
    }

    if (S && (N % 128) == 0 && (A % 128) == 0) {
        char* wsb = (char*)d_ws;
        __bf16* pk  = (__bf16*)wsb;
        float*  prt = (float*)(wsb + packed);

        const int nkb = A / 64, nmb = A / 128;
        pack_kernel<<<dim3(nkb + nmb), 256, 0, stream>>>(addr, Mm, pk, A);

        const int ntt = A / 32;
        fused_fast<<<dim3((N / 128) * S), 256, 0, stream>>>(inp, pk, prt, N, S, ntt);
        combine_kernel<<<dim3((N * 4 + 255) / 256), 256, 0, stream>>>(prt, out, N, S);
    } else {
        float* ws = (float*)d_ws;
        int nsplit = 1;
        for (int s = 8; s >= 2; s >>= 1) {
            if ((size_t)s * N * 16 * sizeof(float) <= ws_size && (A % (s * KVB)) == 0) {
                nsplit = s; break;
            }
        }
        const int direct = (nsplit == 1);
        const int a_per_split = A / nsplit;
        dim3 grid((N / QB) * nsplit);
        fused_dist_softmin<<<grid, 256, 0, stream>>>(inp, addr, Mm, ws, out,
                                                     N, nsplit, a_per_split, direct);
        if (!direct)
            combine16_kernel<<<dim3((N + 255) / 256), 256, 0, stream>>>(ws, out, N, nsplit);
    }
}

// Round 8
// 78.817 us; speedup vs baseline: 3.0943x; 3.0943x over previous
//
#include <hip/hip_runtime.h>
#include <hip/hip_bf16.h>

typedef __bf16 bf8 __attribute__((ext_vector_type(8)));
typedef float f32x4 __attribute__((ext_vector_type(4)));

#define NF 160
#define NC 10
// w = exp(-d/1.1) = exp2(-sqrt(C2 * d^2)), C2 = (log2e/1.1)^2
#define WSCALE (-1.4426950408889634f / 1.1f)
#define C2SCALE (WSCALE * WSCALE)
#define NEG2C2 (-2.0f * C2SCALE)

// ---------------------------------------------------------------------------
__device__ __forceinline__ void gload_lds16(const __bf16* gsrc, __bf16* ldst) {
    __builtin_amdgcn_global_load_lds(
        (const __attribute__((address_space(1))) unsigned int*)gsrc,
        (__attribute__((address_space(3))) unsigned int*)ldst,
        16, 0, 0);
}

// ===========================================================================
// PRE-PASS (R4 layout): K frags per 16-row block b: [kk(5)][lane(64)][8 bf16]
// (5120 B/block); y2*C2 f32; M^T frags per 32-row block: [lane(64)][8 bf16].
// ===========================================================================
__global__ __launch_bounds__(256)
void pack_kernel(const float* __restrict__ addr, const float* __restrict__ Mm,
                 __bf16* __restrict__ wk, float* __restrict__ y2,
                 __bf16* __restrict__ wm, int A)
{
    const int nkb = A / 64;
    const int lane = threadIdx.x & 63;
    const int w    = threadIdx.x >> 6;
    const int l15  = lane & 15;
    const int g    = lane >> 4;

    if ((int)blockIdx.x < nkb) {
        const int b = blockIdx.x * 4 + w;
        const float* row = addr + (size_t)(b * 16 + l15) * NF;
        __bf16* dst = wk + (size_t)b * 2560;
        float ss = 0.f;
        #pragma unroll
        for (int kk = 0; kk < 5; ++kk) {
            float4 lo = *(const float4*)(row + 32 * kk + 4 * g);
            float4 hi = *(const float4*)(row + 32 * kk + 4 * g + 16);
            ss += lo.x*lo.x + lo.y*lo.y + lo.z*lo.z + lo.w*lo.w
                + hi.x*hi.x + hi.y*hi.y + hi.z*hi.z + hi.w*hi.w;
            bf8 f;
            f[0]=(__bf16)lo.x; f[1]=(__bf16)lo.y; f[2]=(__bf16)lo.z; f[3]=(__bf16)lo.w;
            f[4]=(__bf16)hi.x; f[5]=(__bf16)hi.y; f[6]=(__bf16)hi.z; f[7]=(__bf16)hi.w;
            *(bf8*)(dst + ((size_t)kk * 64 + lane) * 8) = f;
        }
        ss += __shfl_xor(ss, 16, 64);
        ss += __shfl_xor(ss, 32, 64);
        if (g == 0) y2[b * 16 + l15] = ss * C2SCALE;   // pre-scaled
    } else {
        const int mb = (blockIdx.x - nkb) * 4 + w;
        bf8 f;
        #pragma unroll
        for (int e = 0; e < 8; ++e) {
            int r = mb * 32 + 4 * g + (e & 3) + 16 * (e >> 2);
            float v = (l15 < NC) ? Mm[(size_t)r * NC + l15] : (l15 == NC ? 1.0f : 0.0f);
            f[e] = (__bf16)v;
        }
        *(bf8*)(wm + (size_t)mb * 512 + (size_t)lane * 8) = f;
    }
}

// ===========================================================================
// MAIN: R4 geometry (64-row tiles, LDS 2x20480, 4 waves x 32 queries) plus a
// deferred-finish software pipeline: step k issues QK-MFMAs, then runs the
// {sqrt/exp2/pack/PV} finish of step k-1 from carried registers. MFMA pipe
// (step k) and VALU/trans pipe (step k-1) overlap within each wave.
// ===========================================================================
__global__ __launch_bounds__(256)
void fused_fast(const float* __restrict__ inp,
                const __bf16* __restrict__ wk,
                const float* __restrict__ y2,
                const __bf16* __restrict__ wm,
                float* __restrict__ part,
                int N, int S, int ntiles)
{
    __shared__ __align__(16) __bf16 kbuf[2][10240];   // 2 x 20480 B

    const int bid   = blockIdx.x;
    const int split = bid % S;
    const int qblk  = bid / S;
    const int t     = threadIdx.x;
    const int lane  = t & 63;
    const int wave  = t >> 6;
    const int l15   = lane & 15;
    const int g     = lane >> 4;

    // ---- hoist Q fragments + x2*C2 (per wave's own 32 queries)
    const int qbase = qblk * 128 + wave * 32;
    bf8 qfrag[2][5];
    float x2q[2];
    #pragma unroll
    for (int qf = 0; qf < 2; ++qf) {
        const float* qrow = inp + (size_t)(qbase + qf * 16 + l15) * NF;
        float ss = 0.f;
        #pragma unroll
        for (int kk = 0; kk < 5; ++kk) {
            float4 lo = *(const float4*)(qrow + 32 * kk + 4 * g);
            float4 hi = *(const float4*)(qrow + 32 * kk + 4 * g + 16);
            ss += lo.x*lo.x + lo.y*lo.y + lo.z*lo.z + lo.w*lo.w
                + hi.x*hi.x + hi.y*hi.y + hi.z*hi.z + hi.w*hi.w;
            bf8 f;
            f[0]=(__bf16)lo.x; f[1]=(__bf16)lo.y; f[2]=(__bf16)lo.z; f[3]=(__bf16)lo.w;
            f[4]=(__bf16)hi.x; f[5]=(__bf16)hi.y; f[6]=(__bf16)hi.z; f[7]=(__bf16)hi.w;
            qfrag[qf][kk] = f;
        }
        ss += __shfl_xor(ss, 16, 64);
        ss += __shfl_xor(ss, 32, 64);
        x2q[qf] = ss * C2SCALE;
    }

    f32x4 acc[2];
    acc[0] = (f32x4){0.f,0.f,0.f,0.f};
    acc[1] = (f32x4){0.f,0.f,0.f,0.f};

    const size_t a0    = (size_t)split * ((size_t)ntiles * 64);
    const __bf16* ksrc = wk + a0 * 160;
    const float*  y2s  = y2 + a0;
    const __bf16* msrc = wm + (a0 >> 5) * 512;

    // ---- prologue: stage tile 0
    #pragma unroll
    for (int i = 0; i < 5; ++i)
        gload_lds16(ksrc + ((size_t)i * 256 + t) * 8, &kbuf[0][((size_t)i * 256 + t) * 8]);
    asm volatile("s_waitcnt vmcnt(0)" ::: "memory");
    __builtin_amdgcn_s_barrier();

    // ---- pipeline state (finish of step k-1 runs during step k)
    f32x4 sp00, sp01, sp10, sp11;   // QK results: sp[qf][m-half]
    bf8   mf_p;                     // M^T fragment of the pending step
    float y2p[8];                   // y2 of the pending step

#define FINISH_PREV() do {                                                     \
    bf8 p0, p1;                                                                \
    _Pragma("unroll")                                                          \
    for (int r = 0; r < 4; ++r) {                                              \
        float d2a = fmaf(sp00[r], NEG2C2, x2q[0] + y2p[r]);                    \
        float d2b = fmaf(sp01[r], NEG2C2, x2q[0] + y2p[4 + r]);                \
        p0[r]     = (__bf16)__builtin_amdgcn_exp2f(-__builtin_amdgcn_sqrtf(d2a)); \
        p0[4 + r] = (__bf16)__builtin_amdgcn_exp2f(-__builtin_amdgcn_sqrtf(d2b)); \
        float d2c = fmaf(sp10[r], NEG2C2, x2q[1] + y2p[r]);                    \
        float d2d = fmaf(sp11[r], NEG2C2, x2q[1] + y2p[4 + r]);                \
        p1[r]     = (__bf16)__builtin_amdgcn_exp2f(-__builtin_amdgcn_sqrtf(d2c)); \
        p1[4 + r] = (__bf16)__builtin_amdgcn_exp2f(-__builtin_amdgcn_sqrtf(d2d)); \
    }                                                                          \
    acc[0] = __builtin_amdgcn_mfma_f32_16x16x32_bf16(mf_p, p0, acc[0], 0,0,0); \
    acc[1] = __builtin_amdgcn_mfma_f32_16x16x32_bf16(mf_p, p1, acc[1], 0,0,0); \
} while (0)

    int cur = 0;
    for (int tile = 0; tile < ntiles; ++tile) {
        if (tile + 1 < ntiles) {
            const __bf16* nsrc = ksrc + (size_t)(tile + 1) * 10240;
            #pragma unroll
            for (int i = 0; i < 5; ++i)
                gload_lds16(nsrc + ((size_t)i * 256 + t) * 8,
                            &kbuf[cur ^ 1][((size_t)i * 256 + t) * 8]);
        }

        const __bf16* kb = &kbuf[cur][0];
        #pragma unroll
        for (int v = 0; v < 2; ++v) {
            // ---- QK-MFMAs for THIS step (4 interleaved chains)
            bf8 kf[2][5];
            #pragma unroll
            for (int m = 0; m < 2; ++m)
                #pragma unroll
                for (int kk = 0; kk < 5; ++kk)
                    kf[m][kk] = *(const bf8*)(kb + (((size_t)(v*2+m) * 5 + kk) * 64 + lane) * 8);

            f32x4 sn00 = {0.f,0.f,0.f,0.f}, sn01 = {0.f,0.f,0.f,0.f};
            f32x4 sn10 = {0.f,0.f,0.f,0.f}, sn11 = {0.f,0.f,0.f,0.f};
            #pragma unroll
            for (int kk = 0; kk < 5; ++kk) {
                sn00 = __builtin_amdgcn_mfma_f32_16x16x32_bf16(kf[0][kk], qfrag[0][kk], sn00, 0,0,0);
                sn01 = __builtin_amdgcn_mfma_f32_16x16x32_bf16(kf[1][kk], qfrag[0][kk], sn01, 0,0,0);
                sn10 = __builtin_amdgcn_mfma_f32_16x16x32_bf16(kf[0][kk], qfrag[1][kk], sn10, 0,0,0);
                sn11 = __builtin_amdgcn_mfma_f32_16x16x32_bf16(kf[1][kk], qfrag[1][kk], sn11, 0,0,0);
            }

            // ---- finish of the PREVIOUS step (trans+pack+PV), overlaps MFMAs
            if (v > 0 || tile > 0) FINISH_PREV();

            // ---- carry: this step becomes the pending step
            mf_p = *(const bf8*)(msrc + ((size_t)tile * 2 + v) * 512 + (size_t)lane * 8);
            {
                const float* yp = y2s + tile * 64 + v * 32;
                #pragma unroll
                for (int m = 0; m < 2; ++m) {
                    float4 yv = *(const float4*)(yp + m * 16 + 4 * g);
                    y2p[m*4+0] = yv.x; y2p[m*4+1] = yv.y;
                    y2p[m*4+2] = yv.z; y2p[m*4+3] = yv.w;
                }
            }
            sp00 = sn00; sp01 = sn01; sp10 = sn10; sp11 = sn11;
        }

        asm volatile("s_waitcnt vmcnt(0)" ::: "memory");
        __builtin_amdgcn_s_barrier();
        cur ^= 1;
    }
    FINISH_PREV();   // drain the last step
#undef FINISH_PREV

    // ---- epilogue: partials [S][N][12] (cols 0..9 = num, col 10 = denom)
    #pragma unroll
    for (int qf = 0; qf < 2; ++qf) {
        if (g < 3) {
            const int q = qbase + qf * 16 + l15;
            *(f32x4*)(part + ((size_t)split * N + q) * 12 + 4 * g) = acc[qf];
        }
    }
}

// 4 threads per query, shfl-reduce, lane0-of-4 writes.
__global__ void combine_kernel(const float* __restrict__ ws, float* __restrict__ out,
                               int N, int nsplit)
{
    int gid = blockIdx.x * blockDim.x + threadIdx.x;
    int q = gid >> 2, part = gid & 3;
    if (q >= N) return;
    f32x4 n0 = {0.f,0.f,0.f,0.f}, n1 = {0.f,0.f,0.f,0.f}, n2 = {0.f,0.f,0.f,0.f};
    for (int s = part; s < nsplit; s += 4) {
        const float* p = ws + ((size_t)s * N + q) * 12;
        n0 += *(const f32x4*)(p);
        n1 += *(const f32x4*)(p + 4);
        n2 += *(const f32x4*)(p + 8);
    }
    #pragma unroll
    for (int d = 1; d < 4; d <<= 1) {
        #pragma unroll
        for (int i = 0; i < 4; ++i) {
            n0[i] += __shfl_xor(n0[i], d, 64);
            n1[i] += __shfl_xor(n1[i], d, 64);
            n2[i] += __shfl_xor(n2[i], d, 64);
        }
    }
    if (part == 0) {
        float inv = 1.f / n2[2];
        float o[NC] = {n0[0],n0[1],n0[2],n0[3],n1[0],n1[1],n1[2],n1[3],n2[0],n2[1]};
        #pragma unroll
        for (int c = 0; c < NC; ++c) out[(size_t)q * NC + c] = o[c] * inv;
    }
}

// ===========================================================================
// FALLBACK (round-1 kernel): used only if ws too small for the packed path.
// ===========================================================================
#define QB 64
#define KVB 128
#define KPAD 164
#define MPAD 18

__global__ __launch_bounds__(256, 2)
void fused_dist_softmin(const float* __restrict__ inp,
                        const float* __restrict__ addr,
                        const float* __restrict__ Mm,
                        float* __restrict__ ws,
                        float* __restrict__ outp,
                        int N, int nsplit, int a_per_split, int direct)
{
    __shared__ __align__(16) __bf16 Klds[KVB][KPAD];
    __shared__ __align__(16) __bf16 Mlds[KVB][MPAD];
    __shared__ float y2lds[KVB];
    __shared__ float x2lds[QB];
    __shared__ float redbuf[4][4][16][16];

    const int bid = blockIdx.x;
    int split, qblock;
    if (nsplit == 8) { split = bid & 7; qblock = bid >> 3; }
    else             { split = bid % nsplit; qblock = bid / nsplit; }

    const int t    = threadIdx.x;
    const int lane = t & 63;
    const int wave = t >> 6;
    const int l15  = lane & 15;
    const int g    = lane >> 4;
    const int foff = 4 * g;

    if (t < QB) {
        const float* row = inp + (size_t)(qblock * QB + t) * NF;
        float s = 0.f;
        #pragma unroll
        for (int i = 0; i < NF/4; ++i) {
            float4 v = *(const float4*)(row + 4*i);
            s += v.x*v.x + v.y*v.y + v.z*v.z + v.w*v.w;
        }
        x2lds[t] = s;
    }

    bf8 qfrag[4][5];
    #pragma unroll
    for (int qf = 0; qf < 4; ++qf) {
        const float* qrow = inp + (size_t)(qblock*QB + qf*16 + l15) * NF;
        #pragma unroll
        for (int kk = 0; kk < 5; ++kk) {
            float4 lo = *(const float4*)(qrow + 32*kk + foff);
            float4 hi = *(const float4*)(qrow + 32*kk + foff + 16);
            bf8 f;
            f[0]=(__bf16)lo.x; f[1]=(__bf16)lo.y; f[2]=(__bf16)lo.z; f[3]=(__bf16)lo.w;
            f[4]=(__bf16)hi.x; f[5]=(__bf16)hi.y; f[6]=(__bf16)hi.z; f[7]=(__bf16)hi.w;
            qfrag[qf][kk] = f;
        }
    }

    __syncthreads();
    float x2q[4];
    #pragma unroll
    for (int qf = 0; qf < 4; ++qf) x2q[qf] = x2lds[qf*16 + l15];

    f32x4 acc[4];
    #pragma unroll
    for (int qf = 0; qf < 4; ++qf) acc[qf] = (f32x4){0.f,0.f,0.f,0.f};

    const int wa      = wave * 32;
    const int a_begin = split * a_per_split;
    const int ntiles  = a_per_split / KVB;

    for (int tile = 0; tile < ntiles; ++tile) {
        const int a0 = a_begin + tile * KVB;
        __syncthreads();
        {
            const int r = t >> 1, h = t & 1;
            const float* rowp = addr + (size_t)(a0 + r) * NF + h*80;
            float ss = 0.f;
            #pragma unroll
            for (int i = 0; i < 20; ++i) {
                float4 v = *(const float4*)(rowp + 4*i);
                ss += v.x*v.x + v.y*v.y + v.z*v.z + v.w*v.w;
                union { __bf16 b[4]; uint2 u; } pk2;
                pk2.b[0]=(__bf16)v.x; pk2.b[1]=(__bf16)v.y;
                pk2.b[2]=(__bf16)v.z; pk2.b[3]=(__bf16)v.w;
                *(uint2*)&Klds[r][h*80 + 4*i] = pk2.u;
            }
            ss += __shfl_xor(ss, 1, 64);
            if (h == 0) y2lds[r] = ss;
        }
        for (int j = t; j < KVB*NC; j += 256) {
            int r = j / NC, c = j % NC;
            Mlds[r][c] = (__bf16)Mm[(size_t)(a0 + r)*NC + c];
        }
        for (int j = t; j < KVB*8; j += 256) {
            int r = j >> 3, c = 10 + (j & 7);
            Mlds[r][c] = (c == 10) ? (__bf16)1.0f : (__bf16)0.0f;
        }
        __syncthreads();

        bf8 kfrag[2][5];
        #pragma unroll
        for (int m = 0; m < 2; ++m) {
            const __bf16* krow = &Klds[wa + 16*m + l15][0];
            #pragma unroll
            for (int kk = 0; kk < 5; ++kk) {
                uint2 lo = *(const uint2*)(krow + 32*kk + foff);
                uint2 hi = *(const uint2*)(krow + 32*kk + foff + 16);
                union { unsigned int u[4]; bf8 v; } fr;
                fr.u[0]=lo.x; fr.u[1]=lo.y; fr.u[2]=hi.x; fr.u[3]=hi.y;
                kfrag[m][kk] = fr.v;
            }
        }
        float y2r[8];
        #pragma unroll
        for (int m = 0; m < 2; ++m)
            #pragma unroll
            for (int r = 0; r < 4; ++r)
                y2r[m*4 + r] = y2lds[wa + 16*m + 4*g + r];

        bf8 mfrag;
        #pragma unroll
        for (int e = 0; e < 8; ++e)
            mfrag[e] = Mlds[wa + 4*g + (e & 3) + 16*(e >> 2)][l15];

        #pragma unroll
        for (int qf = 0; qf < 4; ++qf) {
            f32x4 s0 = {0.f,0.f,0.f,0.f}, s1 = {0.f,0.f,0.f,0.f};
            #pragma unroll
            for (int kk = 0; kk < 5; ++kk) {
                s0 = __builtin_amdgcn_mfma_f32_16x16x32_bf16(kfrag[0][kk], qfrag[qf][kk], s0, 0, 0, 0);
                s1 = __builtin_amdgcn_mfma_f32_16x16x32_bf16(kfrag[1][kk], qfrag[qf][kk], s1, 0, 0, 0);
            }
            bf8 p;
            const float xq = x2q[qf];
            #pragma unroll
            for (int r = 0; r < 4; ++r) {
                float d2a = xq + y2r[r]     - 2.f*s0[r];
                float d2b = xq + y2r[4 + r] - 2.f*s1[r];
                float da = __builtin_amdgcn_sqrtf(d2a);
                float db = __builtin_amdgcn_sqrtf(d2b);
                p[r]     = (__bf16)__builtin_amdgcn_exp2f(da * WSCALE);
                p[4 + r] = (__bf16)__builtin_amdgcn_exp2f(db * WSCALE);
            }
            acc[qf] = __builtin_amdgcn_mfma_f32_16x16x32_bf16(mfrag, p, acc[qf], 0, 0, 0);
        }
    }

    #pragma unroll
    for (int qf = 0; qf < 4; ++qf)
        #pragma unroll
        for (int r = 0; r < 4; ++r)
            redbuf[wave][qf][4*g + r][l15] = acc[qf][r];
    __syncthreads();

    const int qf2 = t >> 6;
    const int qq  = (t >> 2) & 15;
    const int cg  = t & 3;
    float v[4];
    #pragma unroll
    for (int i = 0; i < 4; ++i) {
        const int c = cg*4 + i;
        v[i] = redbuf[0][qf2][c][qq] + redbuf[1][qf2][c][qq]
             + redbuf[2][qf2][c][qq] + redbuf[3][qf2][c][qq];
    }
    const int qg = qblock*QB + qf2*16 + qq;
    if (!direct) {
        float4 o; o.x=v[0]; o.y=v[1]; o.z=v[2]; o.w=v[3];
        *(float4*)(ws + ((size_t)split * N + qg) * 16 + cg*4) = o;
    } else {
        float den = redbuf[0][qf2][10][qq] + redbuf[1][qf2][10][qq]
                  + redbuf[2][qf2][10][qq] + redbuf[3][qf2][10][qq];
        float inv = 1.f / den;
        #pragma unroll
        for (int i = 0; i < 4; ++i) {
            int c = cg*4 + i;
            if (c < NC) outp[(size_t)qg * NC + c] = v[i] * inv;
        }
    }
}

__global__ void combine16_kernel(const float* __restrict__ ws, float* __restrict__ out,
                                 int N, int nsplit)
{
    int q = blockIdx.x * blockDim.x + threadIdx.x;
    if (q >= N) return;
    float num[NC];
    #pragma unroll
    for (int c = 0; c < NC; ++c) num[c] = 0.f;
    float den = 0.f;
    for (int s = 0; s < nsplit; ++s) {
        const float* p = ws + ((size_t)s * N + q) * 16;
        #pragma unroll
        for (int c = 0; c < NC; ++c) num[c] += p[c];
        den += p[10];
    }
    float inv = 1.f / den;
    #pragma unroll
    for (int c = 0; c < NC; ++c) out[(size_t)q * NC + c] = num[c] * inv;
}

// ===========================================================================
extern "C" void kernel_launch(void* const* d_in, const int* in_sizes, int n_in,
                              void* d_out, int out_size, void* d_ws, size_t ws_size,
                              hipStream_t stream)
{
    const float* inp  = (const float*)d_in[0];
    const float* addr = (const float*)d_in[1];
    const float* Mm   = (const float*)d_in[2];
    float* out = (float*)d_out;

    const int N = in_sizes[0] / NF;   // 4096
    const int A = in_sizes[1] / NF;   // 32768

    const size_t kbytes = (size_t)A * 320;
    const size_t mbytes = (size_t)(A / 32) * 1024;
    const size_t ybytes = (size_t)A * 4;
    const size_t base   = kbytes + mbytes + ybytes;

    int S = 0;
    const int cand[4] = {32, 64, 16, 8};
    for (int i = 0; i < 4; ++i) {
        int s = cand[i];
        if ((A % (s * 64)) == 0 && base + (size_t)s * N * 48 <= ws_size) { S = s; break; }
    }

    if (S && (N % 128) == 0 && (A % 128) == 0) {
        char* wsb = (char*)d_ws;
        __bf16* wk  = (__bf16*)wsb;
        __bf16* wm  = (__bf16*)(wsb + kbytes);
        float*  y2  = (float*)(wsb + kbytes + mbytes);
        float*  prt = (float*)(wsb + base);

        const int nkb = A / 64, nmb = A / 128;
        pack_kernel<<<dim3(nkb + nmb), 256, 0, stream>>>(addr, Mm, wk, y2, wm, A);

        const int ntiles = A / (S * 64);
        fused_fast<<<dim3((N / 128) * S), 256, 0, stream>>>(inp, wk, y2, wm, prt, N, S, ntiles);
        combine_kernel<<<dim3((N * 4 + 255) / 256), 256, 0, stream>>>(prt, out, N, S);
    } else {
        float* ws = (float*)d_ws;
        int nsplit = 1;
        for (int s = 8; s >= 2; s >>= 1) {
            if ((size_t)s * N * 16 * sizeof(float) <= ws_size && (A % (s * KVB)) == 0) {
                nsplit = s; break;
            }
        }
        const int direct = (nsplit == 1);
        const int a_per_split = A / nsplit;
        dim3 grid((N / QB) * nsplit);
        fused_dist_softmin<<<grid, 256, 0, stream>>>(inp, addr, Mm, ws, out,
                                                     N, nsplit, a_per_split, direct);
        if (!direct)
            combine16_kernel<<<dim3((N + 255) / 256), 256, 0, stream>>>(ws, out, N, nsplit);
    }
}

// Round 9
// 77.064 us; speedup vs baseline: 3.1647x; 1.0227x over previous
//
#include <hip/hip_runtime.h>
#include <hip/hip_bf16.h>

typedef __bf16 bf8 __attribute__((ext_vector_type(8)));
typedef float f32x4 __attribute__((ext_vector_type(4)));

#define NF 160
#define NC 10
// w = exp(-d/1.1) = exp2(-sqrt(C2 * d^2)), C2 = (log2e/1.1)^2
#define WSCALE (-1.4426950408889634f / 1.1f)
#define C2SCALE (WSCALE * WSCALE)
#define NEG2C2 (-2.0f * C2SCALE)

// Unified packed tile: 32 addr rows, 12288 B:
//   [    0,10240): K frags  [half(2)][kk(5)][lane(64)][8 bf16]
//   [10240,11264): M frags  [lane(64)][8 bf16]   (PV A-operand, ones col 10)
//   [11264,11392): y2*C2    f32[32]
//   [11392,12288): zero pad (staging = 768 x 16B = 3 even loads/thread)
#define TILE_E 6144   // bf16 elements
#define TILE_B 12288  // bytes

// ---------------------------------------------------------------------------
__device__ __forceinline__ void gload_lds16(const __bf16* gsrc, __bf16* ldst) {
    __builtin_amdgcn_global_load_lds(
        (const __attribute__((address_space(1))) unsigned int*)gsrc,
        (__attribute__((address_space(3))) unsigned int*)ldst,
        16, 0, 0);
}

__device__ __forceinline__ void stage3(const __bf16* src, __bf16* dst, int t) {
    gload_lds16(src + (size_t)t * 8,          dst + (size_t)t * 8);
    gload_lds16(src + ((size_t)256 + t) * 8,  dst + ((size_t)256 + t) * 8);
    gload_lds16(src + ((size_t)512 + t) * 8,  dst + ((size_t)512 + t) * 8);
}

// ===========================================================================
// PRE-PASS: build unified tiles (verified layout from round 7).
// ===========================================================================
__global__ __launch_bounds__(256)
void pack_kernel(const float* __restrict__ addr, const float* __restrict__ Mm,
                 __bf16* __restrict__ pk, int A)
{
    const int nkb = A / 64;
    const int lane = threadIdx.x & 63;
    const int w    = threadIdx.x >> 6;
    const int l15  = lane & 15;
    const int g    = lane >> 4;

    if ((int)blockIdx.x < nkb) {
        const int b = blockIdx.x * 4 + w;       // 16-row block
        const int p = b >> 1, h = b & 1;        // tile, half
        const float* row = addr + (size_t)(b * 16 + l15) * NF;
        __bf16* dst = pk + (size_t)p * TILE_E + h * 2560;
        float ss = 0.f;
        #pragma unroll
        for (int kk = 0; kk < 5; ++kk) {
            float4 lo = *(const float4*)(row + 32 * kk + 4 * g);
            float4 hi = *(const float4*)(row + 32 * kk + 4 * g + 16);
            ss += lo.x*lo.x + lo.y*lo.y + lo.z*lo.z + lo.w*lo.w
                + hi.x*hi.x + hi.y*hi.y + hi.z*hi.z + hi.w*hi.w;
            bf8 f;
            f[0]=(__bf16)lo.x; f[1]=(__bf16)lo.y; f[2]=(__bf16)lo.z; f[3]=(__bf16)lo.w;
            f[4]=(__bf16)hi.x; f[5]=(__bf16)hi.y; f[6]=(__bf16)hi.z; f[7]=(__bf16)hi.w;
            *(bf8*)(dst + kk * 512 + lane * 8) = f;
        }
        ss += __shfl_xor(ss, 16, 64);
        ss += __shfl_xor(ss, 32, 64);
        if (g == 0)
            ((float*)(pk + (size_t)p * TILE_E + 5632))[h * 16 + l15] = ss * C2SCALE;
    } else {
        const int mb = (blockIdx.x - nkb) * 4 + w;   // tile index (32 rows)
        bf8 f;
        #pragma unroll
        for (int e = 0; e < 8; ++e) {
            int r = mb * 32 + 4 * g + (e & 3) + 16 * (e >> 2);
            float v = (l15 < NC) ? Mm[(size_t)r * NC + l15] : (l15 == NC ? 1.0f : 0.0f);
            f[e] = (__bf16)v;
        }
        *(bf8*)(pk + (size_t)mb * TILE_E + 5120 + lane * 8) = f;
        if (lane < 56) {                              // zero pad 896 B
            uint4 z = {0u, 0u, 0u, 0u};
            *(uint4*)(pk + (size_t)mb * TILE_E + 5696 + lane * 8) = z;
        }
    }
}

// ===========================================================================
// MAIN: T3+T4 pipeline. Per 32-row tile: issue stage(k+1) -> vmcnt(3) (counted:
// only proves stage(k) landed; stage(k+1) stays in flight across the barrier)
// -> bare s_barrier -> compute(k). 3 LDS buffers remove the write-after-read
// race without a second barrier. vmcnt(0) only at the last tile.
// ===========================================================================
__global__ __launch_bounds__(256)
void fused_fast(const float* __restrict__ inp,
                const __bf16* __restrict__ pk,
                float* __restrict__ part,
                int N, int S, int ntt)
{
    __shared__ __align__(16) __bf16 kbuf[3][TILE_E];   // 36,864 B

    const int bid   = blockIdx.x;
    const int split = bid % S;
    const int qblk  = bid / S;
    const int t     = threadIdx.x;
    const int lane  = t & 63;
    const int wave  = t >> 6;
    const int l15   = lane & 15;
    const int g     = lane >> 4;

    // ---- hoist Q fragments + x2*C2 (per wave's own 32 queries)
    const int qbase = qblk * 128 + wave * 32;
    bf8 qfrag[2][5];
    float x2q[2];
    #pragma unroll
    for (int qf = 0; qf < 2; ++qf) {
        const float* qrow = inp + (size_t)(qbase + qf * 16 + l15) * NF;
        float ss = 0.f;
        #pragma unroll
        for (int kk = 0; kk < 5; ++kk) {
            float4 lo = *(const float4*)(qrow + 32 * kk + 4 * g);
            float4 hi = *(const float4*)(qrow + 32 * kk + 4 * g + 16);
            ss += lo.x*lo.x + lo.y*lo.y + lo.z*lo.z + lo.w*lo.w
                + hi.x*hi.x + hi.y*hi.y + hi.z*hi.z + hi.w*hi.w;
            bf8 f;
            f[0]=(__bf16)lo.x; f[1]=(__bf16)lo.y; f[2]=(__bf16)lo.z; f[3]=(__bf16)lo.w;
            f[4]=(__bf16)hi.x; f[5]=(__bf16)hi.y; f[6]=(__bf16)hi.z; f[7]=(__bf16)hi.w;
            qfrag[qf][kk] = f;
        }
        ss += __shfl_xor(ss, 16, 64);
        ss += __shfl_xor(ss, 32, 64);
        x2q[qf] = ss * C2SCALE;
    }

    f32x4 acc[2];
    acc[0] = (f32x4){0.f,0.f,0.f,0.f};
    acc[1] = (f32x4){0.f,0.f,0.f,0.f};

    const int ts = (split * ntt) / S;
    const int nt = ((split + 1) * ntt) / S - ts;
    const __bf16* src = pk + (size_t)ts * TILE_E;

    // ---- prologue: stage tile 0
    stage3(src, &kbuf[0][0], t);

    int idx = 0;   // k % 3
    for (int k = 0; k < nt; ++k) {
        const int nidx = (idx == 2) ? 0 : idx + 1;
        if (k + 1 < nt) {
            stage3(src + (size_t)(k + 1) * TILE_E, &kbuf[nidx][0], t);
            asm volatile("s_waitcnt vmcnt(3)" ::: "memory");   // stage(k) landed
        } else {
            asm volatile("s_waitcnt vmcnt(0)" ::: "memory");   // last tile: drain
        }
        __builtin_amdgcn_s_barrier();    // everyone's stage(k) quarters landed

        const __bf16* kb = &kbuf[idx][0];
        // mf + y2 from LDS (lgkmcnt path)
        bf8 mf = *(const bf8*)(kb + 5120 + lane * 8);
        float y2r[8];
        {
            const float* y2p = (const float*)(kb + 5632);
            #pragma unroll
            for (int m = 0; m < 2; ++m) {
                f32x4 yv = *(const f32x4*)(y2p + m * 16 + 4 * g);
                y2r[m*4+0] = yv[0]; y2r[m*4+1] = yv[1];
                y2r[m*4+2] = yv[2]; y2r[m*4+3] = yv[3];
            }
        }
        bf8 kf[2][5];
        #pragma unroll
        for (int m = 0; m < 2; ++m)
            #pragma unroll
            for (int kk = 0; kk < 5; ++kk)
                kf[m][kk] = *(const bf8*)(kb + m * 2560 + kk * 512 + lane * 8);

        // ---- QK^T: 4 interleaved MFMA chains
        __builtin_amdgcn_s_setprio(1);
        f32x4 s00 = {0.f,0.f,0.f,0.f}, s01 = {0.f,0.f,0.f,0.f};
        f32x4 s10 = {0.f,0.f,0.f,0.f}, s11 = {0.f,0.f,0.f,0.f};
        #pragma unroll
        for (int kk = 0; kk < 5; ++kk) {
            s00 = __builtin_amdgcn_mfma_f32_16x16x32_bf16(kf[0][kk], qfrag[0][kk], s00, 0,0,0);
            s01 = __builtin_amdgcn_mfma_f32_16x16x32_bf16(kf[1][kk], qfrag[0][kk], s01, 0,0,0);
            s10 = __builtin_amdgcn_mfma_f32_16x16x32_bf16(kf[0][kk], qfrag[1][kk], s10, 0,0,0);
            s11 = __builtin_amdgcn_mfma_f32_16x16x32_bf16(kf[1][kk], qfrag[1][kk], s11, 0,0,0);
        }
        __builtin_amdgcn_s_setprio(0);

        // ---- dist -> weight -> PV
        bf8 p0, p1;
        #pragma unroll
        for (int r = 0; r < 4; ++r) {
            float d2a = fmaf(s00[r], NEG2C2, x2q[0] + y2r[r]);
            float d2b = fmaf(s01[r], NEG2C2, x2q[0] + y2r[4 + r]);
            p0[r]     = (__bf16)__builtin_amdgcn_exp2f(-__builtin_amdgcn_sqrtf(d2a));
            p0[4 + r] = (__bf16)__builtin_amdgcn_exp2f(-__builtin_amdgcn_sqrtf(d2b));
            float d2c = fmaf(s10[r], NEG2C2, x2q[1] + y2r[r]);
            float d2d = fmaf(s11[r], NEG2C2, x2q[1] + y2r[4 + r]);
            p1[r]     = (__bf16)__builtin_amdgcn_exp2f(-__builtin_amdgcn_sqrtf(d2c));
            p1[4 + r] = (__bf16)__builtin_amdgcn_exp2f(-__builtin_amdgcn_sqrtf(d2d));
        }
        acc[0] = __builtin_amdgcn_mfma_f32_16x16x32_bf16(mf, p0, acc[0], 0,0,0);
        acc[1] = __builtin_amdgcn_mfma_f32_16x16x32_bf16(mf, p1, acc[1], 0,0,0);

        idx = nidx;
    }

    // ---- epilogue: partials [S][N][12] (cols 0..9 = num, col 10 = denom)
    #pragma unroll
    for (int qf = 0; qf < 2; ++qf) {
        if (g < 3) {
            const int q = qbase + qf * 16 + l15;
            *(f32x4*)(part + ((size_t)split * N + q) * 12 + 4 * g) = acc[qf];
        }
    }
}

// 4 threads per query, shfl-reduce, lane0-of-4 writes.
__global__ void combine_kernel(const float* __restrict__ ws, float* __restrict__ out,
                               int N, int nsplit)
{
    int gid = blockIdx.x * blockDim.x + threadIdx.x;
    int q = gid >> 2, part = gid & 3;
    if (q >= N) return;
    f32x4 n0 = {0.f,0.f,0.f,0.f}, n1 = {0.f,0.f,0.f,0.f}, n2 = {0.f,0.f,0.f,0.f};
    for (int s = part; s < nsplit; s += 4) {
        const float* p = ws + ((size_t)s * N + q) * 12;
        n0 += *(const f32x4*)(p);
        n1 += *(const f32x4*)(p + 4);
        n2 += *(const f32x4*)(p + 8);
    }
    #pragma unroll
    for (int d = 1; d < 4; d <<= 1) {
        #pragma unroll
        for (int i = 0; i < 4; ++i) {
            n0[i] += __shfl_xor(n0[i], d, 64);
            n1[i] += __shfl_xor(n1[i], d, 64);
            n2[i] += __shfl_xor(n2[i], d, 64);
        }
    }
    if (part == 0) {
        float inv = 1.f / n2[2];
        float o[NC] = {n0[0],n0[1],n0[2],n0[3],n1[0],n1[1],n1[2],n1[3],n2[0],n2[1]};
        #pragma unroll
        for (int c = 0; c < NC; ++c) out[(size_t)q * NC + c] = o[c] * inv;
    }
}

// ===========================================================================
// FALLBACK (round-1 kernel): used only if ws too small for the packed path.
// ===========================================================================
#define QB 64
#define KVB 128
#define KPAD 164
#define MPAD 18

__global__ __launch_bounds__(256, 2)
void fused_dist_softmin(const float* __restrict__ inp,
                        const float* __restrict__ addr,
                        const float* __restrict__ Mm,
                        float* __restrict__ ws,
                        float* __restrict__ outp,
                        int N, int nsplit, int a_per_split, int direct)
{
    __shared__ __align__(16) __bf16 Klds[KVB][KPAD];
    __shared__ __align__(16) __bf16 Mlds[KVB][MPAD];
    __shared__ float y2lds[KVB];
    __shared__ float x2lds[QB];
    __shared__ float redbuf[4][4][16][16];

    const int bid = blockIdx.x;
    int split, qblock;
    if (nsplit == 8) { split = bid & 7; qblock = bid >> 3; }
    else             { split = bid % nsplit; qblock = bid / nsplit; }

    const int t    = threadIdx.x;
    const int lane = t & 63;
    const int wave = t >> 6;
    const int l15  = lane & 15;
    const int g    = lane >> 4;
    const int foff = 4 * g;

    if (t < QB) {
        const float* row = inp + (size_t)(qblock * QB + t) * NF;
        float s = 0.f;
        #pragma unroll
        for (int i = 0; i < NF/4; ++i) {
            float4 v = *(const float4*)(row + 4*i);
            s += v.x*v.x + v.y*v.y + v.z*v.z + v.w*v.w;
        }
        x2lds[t] = s;
    }

    bf8 qfrag[4][5];
    #pragma unroll
    for (int qf = 0; qf < 4; ++qf) {
        const float* qrow = inp + (size_t)(qblock*QB + qf*16 + l15) * NF;
        #pragma unroll
        for (int kk = 0; kk < 5; ++kk) {
            float4 lo = *(const float4*)(qrow + 32*kk + foff);
            float4 hi = *(const float4*)(qrow + 32*kk + foff + 16);
            bf8 f;
            f[0]=(__bf16)lo.x; f[1]=(__bf16)lo.y; f[2]=(__bf16)lo.z; f[3]=(__bf16)lo.w;
            f[4]=(__bf16)hi.x; f[5]=(__bf16)hi.y; f[6]=(__bf16)hi.z; f[7]=(__bf16)hi.w;
            qfrag[qf][kk] = f;
        }
    }

    __syncthreads();
    float x2q[4];
    #pragma unroll
    for (int qf = 0; qf < 4; ++qf) x2q[qf] = x2lds[qf*16 + l15];

    f32x4 acc[4];
    #pragma unroll
    for (int qf = 0; qf < 4; ++qf) acc[qf] = (f32x4){0.f,0.f,0.f,0.f};

    const int wa      = wave * 32;
    const int a_begin = split * a_per_split;
    const int ntiles  = a_per_split / KVB;

    for (int tile = 0; tile < ntiles; ++tile) {
        const int a0 = a_begin + tile * KVB;
        __syncthreads();
        {
            const int r = t >> 1, h = t & 1;
            const float* rowp = addr + (size_t)(a0 + r) * NF + h*80;
            float ss = 0.f;
            #pragma unroll
            for (int i = 0; i < 20; ++i) {
                float4 v = *(const float4*)(rowp + 4*i);
                ss += v.x*v.x + v.y*v.y + v.z*v.z + v.w*v.w;
                union { __bf16 b[4]; uint2 u; } pk2;
                pk2.b[0]=(__bf16)v.x; pk2.b[1]=(__bf16)v.y;
                pk2.b[2]=(__bf16)v.z; pk2.b[3]=(__bf16)v.w;
                *(uint2*)&Klds[r][h*80 + 4*i] = pk2.u;
            }
            ss += __shfl_xor(ss, 1, 64);
            if (h == 0) y2lds[r] = ss;
        }
        for (int j = t; j < KVB*NC; j += 256) {
            int r = j / NC, c = j % NC;
            Mlds[r][c] = (__bf16)Mm[(size_t)(a0 + r)*NC + c];
        }
        for (int j = t; j < KVB*8; j += 256) {
            int r = j >> 3, c = 10 + (j & 7);
            Mlds[r][c] = (c == 10) ? (__bf16)1.0f : (__bf16)0.0f;
        }
        __syncthreads();

        bf8 kfrag[2][5];
        #pragma unroll
        for (int m = 0; m < 2; ++m) {
            const __bf16* krow = &Klds[wa + 16*m + l15][0];
            #pragma unroll
            for (int kk = 0; kk < 5; ++kk) {
                uint2 lo = *(const uint2*)(krow + 32*kk + foff);
                uint2 hi = *(const uint2*)(krow + 32*kk + foff + 16);
                union { unsigned int u[4]; bf8 v; } fr;
                fr.u[0]=lo.x; fr.u[1]=lo.y; fr.u[2]=hi.x; fr.u[3]=hi.y;
                kfrag[m][kk] = fr.v;
            }
        }
        float y2r[8];
        #pragma unroll
        for (int m = 0; m < 2; ++m)
            #pragma unroll
            for (int r = 0; r < 4; ++r)
                y2r[m*4 + r] = y2lds[wa + 16*m + 4*g + r];

        bf8 mfrag;
        #pragma unroll
        for (int e = 0; e < 8; ++e)
            mfrag[e] = Mlds[wa + 4*g + (e & 3) + 16*(e >> 2)][l15];

        #pragma unroll
        for (int qf = 0; qf < 4; ++qf) {
            f32x4 s0 = {0.f,0.f,0.f,0.f}, s1 = {0.f,0.f,0.f,0.f};
            #pragma unroll
            for (int kk = 0; kk < 5; ++kk) {
                s0 = __builtin_amdgcn_mfma_f32_16x16x32_bf16(kfrag[0][kk], qfrag[qf][kk], s0, 0, 0, 0);
                s1 = __builtin_amdgcn_mfma_f32_16x16x32_bf16(kfrag[1][kk], qfrag[qf][kk], s1, 0, 0, 0);
            }
            bf8 p;
            const float xq = x2q[qf];
            #pragma unroll
            for (int r = 0; r < 4; ++r) {
                float d2a = xq + y2r[r]     - 2.f*s0[r];
                float d2b = xq + y2r[4 + r] - 2.f*s1[r];
                float da = __builtin_amdgcn_sqrtf(d2a);
                float db = __builtin_amdgcn_sqrtf(d2b);
                p[r]     = (__bf16)__builtin_amdgcn_exp2f(da * WSCALE);
                p[4 + r] = (__bf16)__builtin_amdgcn_exp2f(db * WSCALE);
            }
            acc[qf] = __builtin_amdgcn_mfma_f32_16x16x32_bf16(mfrag, p, acc[qf], 0, 0, 0);
        }
    }

    #pragma unroll
    for (int qf = 0; qf < 4; ++qf)
        #pragma unroll
        for (int r = 0; r < 4; ++r)
            redbuf[wave][qf][4*g + r][l15] = acc[qf][r];
    __syncthreads();

    const int qf2 = t >> 6;
    const int qq  = (t >> 2) & 15;
    const int cg  = t & 3;
    float v[4];
    #pragma unroll
    for (int i = 0; i < 4; ++i) {
        const int c = cg*4 + i;
        v[i] = redbuf[0][qf2][c][qq] + redbuf[1][qf2][c][qq]
             + redbuf[2][qf2][c][qq] + redbuf[3][qf2][c][qq];
    }
    const int qg = qblock*QB + qf2*16 + qq;
    if (!direct) {
        float4 o; o.x=v[0]; o.y=v[1]; o.z=v[2]; o.w=v[3];
        *(float4*)(ws + ((size_t)split * N + qg) * 16 + cg*4) = o;
    } else {
        float den = redbuf[0][qf2][10][qq] + redbuf[1][qf2][10][qq]
                  + redbuf[2][qf2][10][qq] + redbuf[3][qf2][10][qq];
        float inv = 1.f / den;
        #pragma unroll
        for (int i = 0; i < 4; ++i) {
            int c = cg*4 + i;
            if (c < NC) outp[(size_t)qg * NC + c] = v[i] * inv;
        }
    }
}

__global__ void combine16_kernel(const float* __restrict__ ws, float* __restrict__ out,
                                 int N, int nsplit)
{
    int q = blockIdx.x * blockDim.x + threadIdx.x;
    if (q >= N) return;
    float num[NC];
    #pragma unroll
    for (int c = 0; c < NC; ++c) num[c] = 0.f;
    float den = 0.f;
    for (int s = 0; s < nsplit; ++s) {
        const float* p = ws + ((size_t)s * N + q) * 16;
        #pragma unroll
        for (int c = 0; c < NC; ++c) num[c] += p[c];
        den += p[10];
    }
    float inv = 1.f / den;
    #pragma unroll
    for (int c = 0; c < NC; ++c) out[(size_t)q * NC + c] = num[c] * inv;
}

// ===========================================================================
extern "C" void kernel_launch(void* const* d_in, const int* in_sizes, int n_in,
                              void* d_out, int out_size, void* d_ws, size_t ws_size,
                              hipStream_t stream)
{
    const float* inp  = (const float*)d_in[0];
    const float* addr = (const float*)d_in[1];
    const float* Mm   = (const float*)d_in[2];
    float* out = (float*)d_out;

    const int N = in_sizes[0] / NF;   // 4096
    const int A = in_sizes[1] / NF;   // 32768

    const size_t packed = (size_t)(A / 32) * TILE_B;

    int S = 0;
    const int cand[4] = {32, 16, 8, 4};
    for (int i = 0; i < 4; ++i) {
        int s = cand[i];
        if (packed + (size_t)s * N * 48 <= ws_size) { S = s; break; }
    }

    if (S && (N % 128) == 0 && (A % 128) == 0) {
        char* wsb = (char*)d_ws;
        __bf16* pk  = (__bf16*)wsb;
        float*  prt = (float*)(wsb + packed);

        const int nkb = A / 64, nmb = A / 128;
        pack_kernel<<<dim3(nkb + nmb), 256, 0, stream>>>(addr, Mm, pk, A);

        const int ntt = A / 32;
        fused_fast<<<dim3((N / 128) * S), 256, 0, stream>>>(inp, pk, prt, N, S, ntt);
        combine_kernel<<<dim3((N * 4 + 255) / 256), 256, 0, stream>>>(prt, out, N, S);
    } else {
        float* ws = (float*)d_ws;
        int nsplit = 1;
        for (int s = 8; s >= 2; s >>= 1) {
            if ((size_t)s * N * 16 * sizeof(float) <= ws_size && (A % (s * KVB)) == 0) {
                nsplit = s; break;
            }
        }
        const int direct = (nsplit == 1);
        const int a_per_split = A / nsplit;
        dim3 grid((N / QB) * nsplit);
        fused_dist_softmin<<<grid, 256, 0, stream>>>(inp, addr, Mm, ws, out,
                                                     N, nsplit, a_per_split, direct);
        if (!direct)
            combine16_kernel<<<dim3((N + 255) / 256), 256, 0, stream>>>(ws, out, N, nsplit);
    }
}